// Round 2
// baseline (406.667 us; speedup 1.0000x reference)
//
#include <hip/hip_runtime.h>
#include <math.h>

#define EPSF 1e-5f

__device__ __forceinline__ float sigm(float v){ return 1.f/(1.f+__expf(-v)); }

// device-wide barrier: 224 blocks, generation-counting, cross-XCD safe
__device__ __forceinline__ void gbar(int* cnt, int* gen, int target)
{
    __syncthreads();
    if (threadIdx.x == 0) {
        __threadfence();
        if (atomicAdd(cnt, 1) == 223) {
            atomicExch(cnt, 0);
            __threadfence();
            atomicAdd(gen, 1);
        } else {
            while (__hip_atomic_load(gen, __ATOMIC_ACQUIRE, __HIP_MEMORY_SCOPE_AGENT) < target) {
                __builtin_amdgcn_s_sleep(1);
            }
        }
        __threadfence();
    }
    __syncthreads();
}

// LayerNorm of 4 rows (values hv[4] held by threads t<128); out -> hnS[4][128] (LDS)
__device__ __forceinline__ void ln_rows(const float hv[4],
    const float* __restrict__ lw, const float* __restrict__ lb,
    float* hnS, float* red, int t)
{
    int d = t & 127;
    if (t < 128) {
        float s[4], s2[4];
        #pragma unroll
        for (int r=0;r<4;++r){ s[r]=hv[r]; s2[r]=hv[r]*hv[r]; }
        #pragma unroll
        for (int o=1;o<64;o<<=1){
            #pragma unroll
            for (int r=0;r<4;++r){ s[r]+=__shfl_xor(s[r],o); s2[r]+=__shfl_xor(s2[r],o); }
        }
        if ((t & 63)==0){
            int wid = t>>6;
            #pragma unroll
            for (int r=0;r<4;++r){ red[r*2+wid]=s[r]; red[8+r*2+wid]=s2[r]; }
        }
    }
    __syncthreads();
    if (t < 128) {
        #pragma unroll
        for (int r=0;r<4;++r){
            float S=red[r*2]+red[r*2+1], S2=red[8+r*2]+red[8+r*2+1];
            float mu=S*(1.f/128.f), var=S2*(1.f/128.f)-mu*mu;
            float rr=rsqrtf(var+EPSF);
            hnS[r*128+d]=(hv[r]-mu)*rr*lw[d]+lb[d];
        }
    }
    __syncthreads();
}

// tropical Q,K + classical V + sigmoid gate for 4 rows from hnS (LDS)
__device__ __forceinline__ void qkvg(const float* hnS, int r0, int t,
    const float* __restrict__ wq, const float* __restrict__ bq,
    const float* __restrict__ wk, const float* __restrict__ bk,
    const float* __restrict__ wv, const float* __restrict__ bv,
    const float* __restrict__ gw, const float* __restrict__ gb,
    float* __restrict__ Q, float* __restrict__ Kg, float* __restrict__ V,
    float* __restrict__ g)
{
    int d = t & 127;
    if (t < 128) {
        float qa[4], va[4];
        #pragma unroll
        for (int r=0;r<4;++r){ qa[r]=-1e30f; va[r]=0.f; }
        const float4* q4=(const float4*)(wq+d*128);
        const float4* v4=(const float4*)(wv+d*128);
        for (int i4=0;i4<32;++i4){
            float4 wqv=q4[i4], wvv=v4[i4];
            #pragma unroll
            for (int r=0;r<4;++r){
                float4 a=((const float4*)(hnS+r*128))[i4];
                qa[r]=fmaxf(qa[r],fmaxf(fmaxf(a.x+wqv.x,a.y+wqv.y),fmaxf(a.z+wqv.z,a.w+wqv.w)));
                va[r]=fmaf(a.x,wvv.x,fmaf(a.y,wvv.y,fmaf(a.z,wvv.z,fmaf(a.w,wvv.w,va[r]))));
            }
        }
        #pragma unroll
        for (int r=0;r<4;++r){ int row=r0+r; Q[row*128+d]=qa[r]+bq[d]; V[row*128+d]=va[r]+bv[d]; }
    } else {
        float ka[4];
        #pragma unroll
        for (int r=0;r<4;++r) ka[r]=-1e30f;
        const float4* k4=(const float4*)(wk+d*128);
        for (int i4=0;i4<32;++i4){
            float4 wkv=k4[i4];
            #pragma unroll
            for (int r=0;r<4;++r){
                float4 a=((const float4*)(hnS+r*128))[i4];
                ka[r]=fmaxf(ka[r],fmaxf(fmaxf(a.x+wkv.x,a.y+wkv.y),fmaxf(a.z+wkv.z,a.w+wkv.w)));
            }
        }
        #pragma unroll
        for (int r=0;r<4;++r){ int row=r0+r; Kg[row*128+d]=ka[r]+bk[d]; }
        if (d < 32){
            int r=d>>3, hh=d&7;
            float acc=gb[hh];
            for (int i=0;i<128;++i) acc=fmaf(hnS[r*128+i], gw[hh*128+i], acc);
            g[(r0+r)*8+hh]=sigm(acc);
        }
    }
}

__global__ __launch_bounds__(256, 1) void mega(
    const float* __restrict__ x,
    const float* __restrict__ pw,  const float* __restrict__ pb,
    const float* __restrict__ clsT,const float* __restrict__ pos,
    const float* __restrict__ bng, const float* __restrict__ bnb,
    const float* __restrict__ bnm, const float* __restrict__ bnr,
    const float* __restrict__ n1w, const float* __restrict__ n1b,
    const float* __restrict__ n2w, const float* __restrict__ n2b,
    const float* __restrict__ wq,  const float* __restrict__ bq,
    const float* __restrict__ wk,  const float* __restrict__ bk,
    const float* __restrict__ wv,  const float* __restrict__ bv,
    const float* __restrict__ wo,  const float* __restrict__ bo,
    const float* __restrict__ gw,  const float* __restrict__ gb,
    const float* __restrict__ tmp,
    const float* __restrict__ tuw, const float* __restrict__ tub,
    const float* __restrict__ laA, const float* __restrict__ laC,
    const float* __restrict__ lgG,
    const float* __restrict__ cuw, const float* __restrict__ cub,
    const float* __restrict__ fgw, const float* __restrict__ fgb,
    const float* __restrict__ dnw, const float* __restrict__ dnb,
    const float* __restrict__ fnw, const float* __restrict__ fnb,
    const float* __restrict__ hdw, const float* __restrict__ hdb,
    float* __restrict__ Q, float* __restrict__ Kg, float* __restrict__ V,
    float* __restrict__ g, float* __restrict__ ao,
    float* __restrict__ out, int* cnt, int* gen)
{
    int bid = blockIdx.x, t = threadIdx.x;
    __shared__ __align__(16) float smem[6400];
    const bool rowblk = bid < 197;
    int r0 = bid * 4;
    float hres[4] = {0.f,0.f,0.f,0.f};   // residual stream, register-resident (t<128 of row blocks)

    // ---------------- P1: patch embed + BN + LN1 + QKVG (layer 0) ----------
    if (rowblk) {
        float* pacc = smem;          // [2][4][128]
        float* hnS  = smem + 1024;   // [4][128]
        float* red  = smem + 1536;   // 16
        int d = t & 127, s = t >> 7;
        const float* xb[4];
        #pragma unroll
        for (int r=0;r<4;++r){
            int row=r0+r, b=row/197, l=row-b*197;
            if (l>0){
                int patch=l-1, ph=patch/14, pc=patch-ph*14;
                xb[r] = x + (size_t)b*150528 + ph*3584 + pc*16;
            } else xb[r] = nullptr;
        }
        float acc[4] = {0.f,0.f,0.f,0.f};
        const float4* wd = (const float4*)(pw + d*768);
        for (int k4=0;k4<96;++k4){
            int kk = s*96 + k4;
            float4 w = wd[kk];
            int xoff = (kk>>6)*50176 + ((kk>>2)&15)*224 + (kk&3)*4;   // c*224*224 + rr*224 + cc
            #pragma unroll
            for (int r=0;r<4;++r){
                if (xb[r]){
                    const float* xr = xb[r] + xoff;   // wave-uniform address -> scalar loads
                    acc[r]=fmaf(xr[0],w.x,fmaf(xr[1],w.y,fmaf(xr[2],w.z,fmaf(xr[3],w.w,acc[r]))));
                }
            }
        }
        #pragma unroll
        for (int r=0;r<4;++r) pacc[(s*4+r)*128+d] = acc[r];
        __syncthreads();
        if (t<128){
            #pragma unroll
            for (int r=0;r<4;++r){
                int row=r0+r, b=row/197, l=row-b*197;
                float v = (l==0) ? clsT[d] : (pacc[r*128+d]+pacc[(4+r)*128+d]+pb[d]);
                v += pos[l*128+d];
                v = bng[d]*((v-bnm[d])/(bnr[d]+EPSF))+bnb[d];
                hres[r]=v;
            }
        }
        ln_rows(hres, n1w, n1b, hnS, red, t);
        qkvg(hnS, r0, t, wq, bq, wk, bk, wv, bv, gw, gb, Q, Kg, V, g);
    }
    gbar(cnt,gen,1);

    for (int layer=0; layer<2; ++layer) {
        // ---------------- attention (all 224 blocks busy) ------------------
        {
            float* Ks = smem; float* Vs = smem + 3152;
            int qc = bid % 7, bh = bid / 7, hh2 = bh & 7, b = bh >> 3;
            size_t base = (size_t)(b*197)*128 + hh2*16;
            for (int idx=t; idx<3152; idx+=256){
                int l=idx>>4, j=idx&15;
                Ks[idx]=Kg[base + (size_t)l*128 + j];
                Vs[idx]=V[base + (size_t)l*128 + j];
            }
            __syncthreads();
            int q = qc*32 + (t>>3), j8 = t&7;
            if (q < 197) {
                float Qr[16];
                const float4* qp = (const float4*)(Q + base + (size_t)q*128);
                #pragma unroll
                for (int u=0;u<4;++u){
                    float4 v4v=qp[u];
                    Qr[4*u]=v4v.x; Qr[4*u+1]=v4v.y; Qr[4*u+2]=v4v.z; Qr[4*u+3]=v4v.w;
                }
                float gq = g[(b*197+q)*8+hh2];
                float it = 0.25f / tmp[layer*8+hh2];
                float gg = gq*it, cg = (1.f-gq)*it;
                float m=-1e30f, lsum=0.f, o[16];
                #pragma unroll
                for (int j=0;j<16;++j) o[j]=0.f;
                for (int k=j8;k<197;k+=8){
                    const float* kr = Ks + k*16;
                    float cs=0.f, ts=-1e30f;
                    #pragma unroll
                    for (int j=0;j<16;++j){
                        float kvv=kr[j];
                        cs=fmaf(Qr[j],kvv,cs);
                        ts=fmaxf(ts,Qr[j]+kvv);
                    }
                    float sc=fmaf(gg,ts,cg*cs);
                    if (sc>m){
                        float c=__expf(m-sc);
                        lsum*=c;
                        #pragma unroll
                        for (int j=0;j<16;++j) o[j]*=c;
                        m=sc;
                    }
                    float p=__expf(sc-m);
                    lsum+=p;
                    const float* vr=Vs+k*16;
                    #pragma unroll
                    for (int j=0;j<16;++j) o[j]=fmaf(p,vr[j],o[j]);
                }
                #pragma unroll
                for (int mask=1;mask<8;mask<<=1){
                    float mo=__shfl_xor(m,mask), lo=__shfl_xor(lsum,mask);
                    float mn=fmaxf(m,mo);
                    float ea=__expf(m-mn), eb=__expf(mo-mn);
                    lsum=lsum*ea+lo*eb;
                    #pragma unroll
                    for (int j=0;j<16;++j){
                        float oo=__shfl_xor(o[j],mask);
                        o[j]=o[j]*ea+oo*eb;
                    }
                    m=mn;
                }
                if (j8==0){
                    float inv=1.f/lsum;
                    float* orow=ao+base+(size_t)q*128;
                    #pragma unroll
                    for (int j=0;j<16;++j) orow[j]=o[j]*inv;
                }
            }
        }
        gbar(cnt,gen,2+layer*2);

        // -------- P34: oproj+res+LN2 + FFN(LDS) + dproj+res + next-LN ------
        if (rowblk) {
            float* pacc   = smem;          // 1024
            float* hnS    = smem + 1024;   // 512
            float* red    = smem + 1536;   // 16
            float* fusedS = smem + 1568;   // 1024
            int d = t & 127, s = t >> 7;

            // oproj (128<-128), split-K across thread halves
            {
                float acc[4]={0.f,0.f,0.f,0.f};
                const float4* w4=(const float4*)(wo + layer*16384 + d*128);
                const float4* ar[4];
                #pragma unroll
                for (int r=0;r<4;++r) ar[r]=(const float4*)(ao+(size_t)(r0+r)*128);
                for (int i4=0;i4<16;++i4){
                    int ii=s*16+i4;
                    float4 w=w4[ii];
                    #pragma unroll
                    for (int r=0;r<4;++r){
                        float4 a=ar[r][ii];
                        acc[r]=fmaf(a.x,w.x,fmaf(a.y,w.y,fmaf(a.z,w.z,fmaf(a.w,w.w,acc[r]))));
                    }
                }
                #pragma unroll
                for (int r=0;r<4;++r) pacc[(s*4+r)*128+d]=acc[r];
            }
            __syncthreads();
            if (t<128){
                #pragma unroll
                for (int r=0;r<4;++r)
                    hres[r] += pacc[r*128+d]+pacc[(4+r)*128+d]+bo[layer*128+d];
            }
            ln_rows(hres, n2w+layer*128, n2b+layer*128, hnS, red, t);

            // FFN: tropical unit + lf max/min + exact GELU + fusion gate (f = t)
            {
                float ta[4],ca[4],ga[4];
                #pragma unroll
                for (int r=0;r<4;++r){ ta[r]=-1e30f; ca[r]=0.f; ga[r]=0.f; }
                const float4* t4=(const float4*)(tuw+layer*32768+t*128);
                const float4* c4=(const float4*)(cuw+layer*32768+t*128);
                const float4* f4=(const float4*)(fgw+layer*32768+t*128);
                for (int i4=0;i4<32;++i4){
                    float4 wt=t4[i4],wc=c4[i4],wf=f4[i4];
                    #pragma unroll
                    for (int r=0;r<4;++r){
                        float4 a=((const float4*)(hnS+r*128))[i4];
                        ta[r]=fmaxf(ta[r],fmaxf(fmaxf(a.x+wt.x,a.y+wt.y),fmaxf(a.z+wt.z,a.w+wt.w)));
                        ca[r]=fmaf(a.x,wc.x,fmaf(a.y,wc.y,fmaf(a.z,wc.z,fmaf(a.w,wc.w,ca[r]))));
                        ga[r]=fmaf(a.x,wf.x,fmaf(a.y,wf.y,fmaf(a.z,wf.z,fmaf(a.w,wf.w,ga[r]))));
                    }
                }
                float gl=sigm(lgG[layer*256+t]);
                float lav[8],lcv[8];
                #pragma unroll
                for (int p=0;p<8;++p){ lav[p]=laA[layer*2048+p*256+t]; lcv[p]=laC[layer*2048+p*256+t]; }
                #pragma unroll
                for (int r=0;r<4;++r){
                    float z=ta[r]+tub[layer*256+t];
                    float mx=-1e30f, mn=1e30f;
                    #pragma unroll
                    for (int p=0;p<8;++p){
                        float zp=fmaf(z,lav[p],lcv[p]);
                        mx=fmaxf(mx,zp); mn=fminf(mn,zp);
                    }
                    float trop=gl*mx+(1.f-gl)*mn;
                    float xc=ca[r]+cub[layer*256+t];
                    float cla=0.5f*xc*(1.f+erff(xc*0.70710678118654752f));
                    float gf=sigm(ga[r]+fgb[layer*256+t]);
                    fusedS[r*256+t]=gf*trop+(1.f-gf)*cla;
                }
            }
            __syncthreads();

            // dproj (128<-256), split-K
            {
                float acc2[4]={0.f,0.f,0.f,0.f};
                const float4* w4b=(const float4*)(dnw + layer*32768 + d*256);
                for (int i4=0;i4<32;++i4){
                    int ii=s*32+i4;
                    float4 w=w4b[ii];
                    #pragma unroll
                    for (int r=0;r<4;++r){
                        float4 a=((const float4*)(fusedS+r*256))[ii];
                        acc2[r]=fmaf(a.x,w.x,fmaf(a.y,w.y,fmaf(a.z,w.z,fmaf(a.w,w.w,acc2[r]))));
                    }
                }
                __syncthreads();
                #pragma unroll
                for (int r=0;r<4;++r) pacc[(s*4+r)*128+d]=acc2[r];
            }
            __syncthreads();
            if (t<128){
                #pragma unroll
                for (int r=0;r<4;++r)
                    hres[r] += pacc[r*128+d]+pacc[(4+r)*128+d]+dnb[layer*128+d];
            }
            if (layer==0){
                ln_rows(hres, n1w+128, n1b+128, hnS, red, t);
                qkvg(hnS, r0, t, wq+16384,bq+128, wk+16384,bk+128, wv+16384,bv+128,
                     gw+1024,gb+8, Q,Kg,V,g);
            } else {
                ln_rows(hres, fnw, fnb, hnS, red, t);
                // classifier head for blocks owning a cls row
                int crow=-1, cb2=0;
                #pragma unroll
                for (int r=0;r<4;++r){
                    int row=r0+r;
                    if (row==0 || row==197 || row==394 || row==591){ crow=r; cb2=row/197; }
                }
                if (crow>=0){
                    const float4* hc=(const float4*)(hnS+crow*128);
                    for (int n=t;n<1000;n+=256){
                        const float4* wr=(const float4*)(hdw+(size_t)n*128);
                        float a2=hdb[n];
                        for (int i=0;i<32;++i){
                            float4 w=wr[i], a=hc[i];
                            a2=fmaf(w.x,a.x,fmaf(w.y,a.y,fmaf(w.z,a.z,fmaf(w.w,a.w,a2))));
                        }
                        out[cb2*1000+n]=a2;
                    }
                }
            }
        }
        if (layer==0) gbar(cnt,gen,3);
    }
}

extern "C" void kernel_launch(void* const* d_in, const int* in_sizes, int n_in,
                              void* d_out, int out_size, void* d_ws, size_t ws_size,
                              hipStream_t stream)
{
    const float* x        = (const float*)d_in[0];
    const float* patch_w  = (const float*)d_in[1];
    const float* patch_b  = (const float*)d_in[2];
    const float* cls_tok  = (const float*)d_in[3];
    const float* pos_emb  = (const float*)d_in[4];
    const float* bn_gamma = (const float*)d_in[5];
    const float* bn_beta  = (const float*)d_in[6];
    const float* bn_rmax  = (const float*)d_in[7];
    const float* bn_rrng  = (const float*)d_in[8];
    const float* n1_w     = (const float*)d_in[9];
    const float* n1_b     = (const float*)d_in[10];
    const float* n2_w     = (const float*)d_in[11];
    const float* n2_b     = (const float*)d_in[12];
    const float* wq       = (const float*)d_in[13];
    const float* bq       = (const float*)d_in[14];
    const float* wk       = (const float*)d_in[15];
    const float* bk       = (const float*)d_in[16];
    const float* wv       = (const float*)d_in[17];
    const float* bv       = (const float*)d_in[18];
    const float* wo       = (const float*)d_in[19];
    const float* bo       = (const float*)d_in[20];
    const float* gate_w   = (const float*)d_in[21];
    const float* gate_b   = (const float*)d_in[22];
    const float* temp     = (const float*)d_in[23];
    const float* tu_w     = (const float*)d_in[24];
    const float* tu_b     = (const float*)d_in[25];
    const float* lf_a     = (const float*)d_in[26];
    const float* lf_c     = (const float*)d_in[27];
    const float* lf_gate  = (const float*)d_in[28];
    const float* cu_w     = (const float*)d_in[29];
    const float* cu_b     = (const float*)d_in[30];
    const float* fg_w     = (const float*)d_in[31];
    const float* fg_b     = (const float*)d_in[32];
    const float* dn_w     = (const float*)d_in[33];
    const float* dn_b     = (const float*)d_in[34];
    const float* fn_w     = (const float*)d_in[35];
    const float* fn_b     = (const float*)d_in[36];
    const float* head_w   = (const float*)d_in[37];
    const float* head_b   = (const float*)d_in[38];

    int*   cnt = (int*)d_ws;
    int*   gen = cnt + 1;
    float* buf = (float*)d_ws + 64;
    float* Q   = buf;               // 788*128
    float* Kb  = Q  + 100864;
    float* V   = Kb + 100864;
    float* g   = V  + 100864;       // 788*8
    float* ao  = g  + 6304;         // 788*128

    hipMemsetAsync(d_ws, 0, 8, stream);   // zero barrier counters (capturable)

    mega<<<224, 256, 0, stream>>>(
        x, patch_w, patch_b, cls_tok, pos_emb, bn_gamma, bn_beta, bn_rmax, bn_rrng,
        n1_w, n1_b, n2_w, n2_b, wq, bq, wk, bk, wv, bv, wo, bo, gate_w, gate_b, temp,
        tu_w, tu_b, lf_a, lf_c, lf_gate, cu_w, cu_b, fg_w, fg_b, dn_w, dn_b,
        fn_w, fn_b, head_w, head_b,
        Q, Kb, V, g, ao, (float*)d_out, cnt, gen);
}

// Round 3
// 154.512 us; speedup vs baseline: 2.6319x; 2.6319x over previous
//
#include <hip/hip_runtime.h>
#include <math.h>

#define EPSF 1e-5f

__device__ __forceinline__ float sigm(float v){ return 1.f/(1.f+__expf(-v)); }

// LayerNorm of 4 rows; values hv[4] held by threads t<128; out -> hnS[4][128]
__device__ __forceinline__ void ln_rows(const float hv[4],
    const float* __restrict__ lw, const float* __restrict__ lb,
    float* hnS, float* red, int t)
{
    int d = t & 127;
    if (t < 128) {
        float s[4], s2[4];
        #pragma unroll
        for (int r=0;r<4;++r){ s[r]=hv[r]; s2[r]=hv[r]*hv[r]; }
        #pragma unroll
        for (int o=1;o<64;o<<=1){
            #pragma unroll
            for (int r=0;r<4;++r){ s[r]+=__shfl_xor(s[r],o); s2[r]+=__shfl_xor(s2[r],o); }
        }
        if ((t & 63)==0){
            int wid = t>>6;
            #pragma unroll
            for (int r=0;r<4;++r){ red[r*2+wid]=s[r]; red[8+r*2+wid]=s2[r]; }
        }
    }
    __syncthreads();
    if (t < 128) {
        #pragma unroll
        for (int r=0;r<4;++r){
            float S=red[r*2]+red[r*2+1], S2=red[8+r*2]+red[8+r*2+1];
            float mu=S*(1.f/128.f), var=S2*(1.f/128.f)-mu*mu;
            float rr=rsqrtf(var+EPSF);
            hnS[r*128+d]=(hv[r]-mu)*rr*lw[d]+lb[d];
        }
    }
    __syncthreads();
}

// tropical Q,K + classical V + gate for 4 rows from hnS; 512 threads (8 waves)
__device__ __forceinline__ void qkvg512(const float* hnS, int r0, int t,
    const float* __restrict__ wq, const float* __restrict__ bq,
    const float* __restrict__ wk, const float* __restrict__ bk,
    const float* __restrict__ wv, const float* __restrict__ bv,
    const float* __restrict__ gw, const float* __restrict__ gb,
    float* __restrict__ Q, float* __restrict__ Kg, float* __restrict__ V,
    float* __restrict__ g)
{
    int grp = t >> 7, d = t & 127;
    if (grp == 0) {
        float qa[4]; 
        #pragma unroll
        for (int r=0;r<4;++r) qa[r]=-1e30f;
        const float4* w4=(const float4*)(wq+d*128);
        #pragma unroll 8
        for (int i4=0;i4<32;++i4){
            float4 w=w4[i4];
            #pragma unroll
            for (int r=0;r<4;++r){
                float4 a=((const float4*)(hnS+r*128))[i4];
                qa[r]=fmaxf(qa[r],fmaxf(fmaxf(a.x+w.x,a.y+w.y),fmaxf(a.z+w.z,a.w+w.w)));
            }
        }
        #pragma unroll
        for (int r=0;r<4;++r) Q[(r0+r)*128+d]=qa[r]+bq[d];
    } else if (grp == 1) {
        float ka[4];
        #pragma unroll
        for (int r=0;r<4;++r) ka[r]=-1e30f;
        const float4* w4=(const float4*)(wk+d*128);
        #pragma unroll 8
        for (int i4=0;i4<32;++i4){
            float4 w=w4[i4];
            #pragma unroll
            for (int r=0;r<4;++r){
                float4 a=((const float4*)(hnS+r*128))[i4];
                ka[r]=fmaxf(ka[r],fmaxf(fmaxf(a.x+w.x,a.y+w.y),fmaxf(a.z+w.z,a.w+w.w)));
            }
        }
        #pragma unroll
        for (int r=0;r<4;++r) Kg[(r0+r)*128+d]=ka[r]+bk[d];
    } else if (grp == 2) {
        float va[4]={0.f,0.f,0.f,0.f};
        const float4* w4=(const float4*)(wv+d*128);
        #pragma unroll 8
        for (int i4=0;i4<32;++i4){
            float4 w=w4[i4];
            #pragma unroll
            for (int r=0;r<4;++r){
                float4 a=((const float4*)(hnS+r*128))[i4];
                va[r]=fmaf(a.x,w.x,fmaf(a.y,w.y,fmaf(a.z,w.z,fmaf(a.w,w.w,va[r]))));
            }
        }
        #pragma unroll
        for (int r=0;r<4;++r) V[(r0+r)*128+d]=va[r]+bv[d];
    } else if (d < 32) {
        int r=d>>3, hh=d&7;
        float acc=gb[hh];
        const float4* gv=(const float4*)(gw+hh*128);
        const float4* av=(const float4*)(hnS+r*128);
        #pragma unroll 8
        for (int i=0;i<32;++i){
            float4 w=gv[i], a=av[i];
            acc=fmaf(a.x,w.x,fmaf(a.y,w.y,fmaf(a.z,w.z,fmaf(a.w,w.w,acc))));
        }
        g[(r0+r)*8+hh]=sigm(acc);
    }
}

// ---------------------------------------------------------------------------
// K1: patchify + patch embed + BN + LN1 + QKVG(layer0).  197 blocks x 512
// ---------------------------------------------------------------------------
__global__ __launch_bounds__(512) void k_p1(
    const float* __restrict__ x, const float* __restrict__ pw, const float* __restrict__ pb,
    const float* __restrict__ clsT, const float* __restrict__ pos,
    const float* __restrict__ bng, const float* __restrict__ bnb,
    const float* __restrict__ bnm, const float* __restrict__ bnr,
    const float* __restrict__ n1w, const float* __restrict__ n1b,
    const float* __restrict__ wq, const float* __restrict__ bq,
    const float* __restrict__ wk, const float* __restrict__ bk,
    const float* __restrict__ wv, const float* __restrict__ bv,
    const float* __restrict__ gw, const float* __restrict__ gb,
    float* __restrict__ h, float* __restrict__ Q, float* __restrict__ Kg,
    float* __restrict__ V, float* __restrict__ g)
{
    __shared__ __align__(16) float xp[4*768];
    __shared__ __align__(16) float pacc[16*128];
    __shared__ __align__(16) float hnS[512];
    __shared__ float red[16];
    int t = threadIdx.x, r0 = blockIdx.x * 4;

    // stage patches (coalesced)
    #pragma unroll
    for (int r=0;r<4;++r){
        int row=r0+r, b=row/197, l=row-b*197;
        if (l>0){
            int patch=l-1, ph=patch/14, pc=patch-ph*14;
            const float* xb = x + (size_t)b*150528 + ph*3584 + pc*16;
            for (int i=t;i<768;i+=512){
                int c=i>>8, rr=(i>>4)&15, cc=i&15;
                xp[r*768+i] = xb[c*50176 + rr*224 + cc];
            }
        }
    }
    __syncthreads();

    // patch GEMM, split-K=4
    {
        int d = t & 127, s = t >> 7;
        float acc[4]={0.f,0.f,0.f,0.f};
        const float4* w4=(const float4*)(pw + d*768);
        #pragma unroll 4
        for (int i4=0;i4<48;++i4){
            int kk = s*48+i4;
            float4 w=w4[kk];
            #pragma unroll
            for (int r=0;r<4;++r){
                float4 a=((const float4*)(xp+r*768))[kk];
                acc[r]=fmaf(a.x,w.x,fmaf(a.y,w.y,fmaf(a.z,w.z,fmaf(a.w,w.w,acc[r]))));
            }
        }
        #pragma unroll
        for (int r=0;r<4;++r) pacc[(s*4+r)*128+d]=acc[r];
    }
    __syncthreads();

    float hres[4]={0.f,0.f,0.f,0.f};
    if (t < 128){
        int d=t;
        #pragma unroll
        for (int r=0;r<4;++r){
            int row=r0+r, b=row/197, l=row-b*197;
            float v = (l==0) ? clsT[d]
                    : (pacc[r*128+d]+pacc[(4+r)*128+d]+pacc[(8+r)*128+d]+pacc[(12+r)*128+d]+pb[d]);
            v += pos[l*128+d];
            v = bng[d]*((v-bnm[d])/(bnr[d]+EPSF))+bnb[d];
            hres[r]=v;
            h[row*128+d]=v;
        }
    }
    ln_rows(hres, n1w, n1b, hnS, red, t);
    qkvg512(hnS, r0, t, wq,bq,wk,bk,wv,bv,gw,gb, Q,Kg,V,g);
}

// ---------------------------------------------------------------------------
// K2: fused attention.  224 blocks x 256 threads (8 lanes per query)
// ---------------------------------------------------------------------------
__global__ __launch_bounds__(256) void k_attn(
    const float* __restrict__ Qd, const float* __restrict__ Kd,
    const float* __restrict__ Vd, const float* __restrict__ gd,
    const float* __restrict__ tempL, float* __restrict__ ao)
{
    __shared__ __align__(16) float Ks[197*16];
    __shared__ __align__(16) float Vs[197*16];
    int bid = blockIdx.x, t = threadIdx.x;
    int qc = bid % 7, bh = bid / 7, hh = bh & 7, b = bh >> 3;
    size_t base = (size_t)(b*197)*128 + hh*16;

    {
        const float4* ksrc=(const float4*)(Kd+base);
        const float4* vsrc=(const float4*)(Vd+base);
        float4* kdst=(float4*)Ks; float4* vdst=(float4*)Vs;
        for (int idx=t; idx<788; idx+=256){
            int l=idx>>2, jj=idx&3;
            kdst[idx]=ksrc[l*32+jj];
            vdst[idx]=vsrc[l*32+jj];
        }
    }
    __syncthreads();

    int q = qc*32 + (t>>3), j8 = t&7;
    if (q >= 197) return;

    float Qr[16];
    {
        const float4* qp=(const float4*)(Qd+base+(size_t)q*128);
        #pragma unroll
        for (int u=0;u<4;++u){
            float4 v=qp[u];
            Qr[4*u]=v.x; Qr[4*u+1]=v.y; Qr[4*u+2]=v.z; Qr[4*u+3]=v.w;
        }
    }
    float gq = gd[(b*197+q)*8+hh];
    float it = 0.25f / tempL[hh];
    float gg = gq*it, cg = (1.f-gq)*it;

    float m=-1e30f, lsum=0.f, o[16];
    #pragma unroll
    for (int j=0;j<16;++j) o[j]=0.f;

    for (int k=j8;k<197;k+=8){
        const float* kr=Ks+k*16;
        float cs=0.f, ts=-1e30f;
        #pragma unroll
        for (int j=0;j<16;++j){
            float kv=kr[j];
            cs=fmaf(Qr[j],kv,cs);
            ts=fmaxf(ts,Qr[j]+kv);
        }
        float sc=fmaf(gg,ts,cg*cs);
        if (sc>m){
            float c=__expf(m-sc);
            lsum*=c;
            #pragma unroll
            for (int j=0;j<16;++j) o[j]*=c;
            m=sc;
        }
        float p=__expf(sc-m);
        lsum+=p;
        const float* vr=Vs+k*16;
        #pragma unroll
        for (int j=0;j<16;++j) o[j]=fmaf(p,vr[j],o[j]);
    }

    #pragma unroll
    for (int mask=1;mask<8;mask<<=1){
        float mo=__shfl_xor(m,mask), lo=__shfl_xor(lsum,mask);
        float mn=fmaxf(m,mo);
        float ea=__expf(m-mn), eb=__expf(mo-mn);
        lsum=lsum*ea+lo*eb;
        #pragma unroll
        for (int j=0;j<16;++j){
            float oo=__shfl_xor(o[j],mask);
            o[j]=o[j]*ea+oo*eb;
        }
        m=mn;
    }

    if (j8==0){
        float inv=1.f/lsum;
        float* orow=ao+base+(size_t)q*128;
        #pragma unroll
        for (int j=0;j<16;++j) orow[j]=o[j]*inv;
    }
}

// ---------------------------------------------------------------------------
// K3: oproj+res+LN2 + FFN + dproj+res + next-LN + (QKVG | head)
// 197 blocks x 512 threads
// ---------------------------------------------------------------------------
template <int FINAL>
__global__ __launch_bounds__(512) void k_p34(
    const float* __restrict__ ao, float* __restrict__ h,
    const float* __restrict__ wo, const float* __restrict__ bo,
    const float* __restrict__ n2w, const float* __restrict__ n2b,
    const float* __restrict__ tuw, const float* __restrict__ tub,
    const float* __restrict__ laA, const float* __restrict__ laC,
    const float* __restrict__ lgG,
    const float* __restrict__ cuw, const float* __restrict__ cub,
    const float* __restrict__ fgw, const float* __restrict__ fgb,
    const float* __restrict__ dnw, const float* __restrict__ dnb,
    const float* __restrict__ nlw, const float* __restrict__ nlb,
    const float* __restrict__ wq, const float* __restrict__ bq,
    const float* __restrict__ wk, const float* __restrict__ bk,
    const float* __restrict__ wv, const float* __restrict__ bv,
    const float* __restrict__ gw, const float* __restrict__ gb,
    float* __restrict__ Q, float* __restrict__ Kg, float* __restrict__ V,
    float* __restrict__ g,
    const float* __restrict__ hdw, const float* __restrict__ hdb,
    float* __restrict__ out)
{
    __shared__ __align__(16) float aoS[512];
    __shared__ __align__(16) float pacc[16*128];
    __shared__ __align__(16) float hnS[512];
    __shared__ __align__(16) float fusedS[1024];
    __shared__ float red[16];
    int t = threadIdx.x, r0 = blockIdx.x * 4;
    int d = t & 127, s = t >> 7;

    aoS[t] = ao[r0*128 + t];
    __syncthreads();

    // oproj split-K=4 (32 floats each)
    {
        float acc[4]={0.f,0.f,0.f,0.f};
        const float4* w4=(const float4*)(wo + d*128);
        #pragma unroll
        for (int i4=0;i4<8;++i4){
            int ii=s*8+i4;
            float4 w=w4[ii];
            #pragma unroll
            for (int r=0;r<4;++r){
                float4 a=((const float4*)(aoS+r*128))[ii];
                acc[r]=fmaf(a.x,w.x,fmaf(a.y,w.y,fmaf(a.z,w.z,fmaf(a.w,w.w,acc[r]))));
            }
        }
        #pragma unroll
        for (int r=0;r<4;++r) pacc[(s*4+r)*128+d]=acc[r];
    }
    __syncthreads();

    float hres[4]={0.f,0.f,0.f,0.f};
    if (t<128){
        #pragma unroll
        for (int r=0;r<4;++r)
            hres[r]=h[(r0+r)*128+d]+pacc[r*128+d]+pacc[(4+r)*128+d]+pacc[(8+r)*128+d]+pacc[(12+r)*128+d]+bo[d];
    }
    ln_rows(hres, n2w, n2b, hnS, red, t);

    // FFN: f = t&255; each thread does 2 rows (rr2 selects pair), full-K
    {
        int f = t & 255, rr2 = t >> 8;
        float ta[2]={-1e30f,-1e30f}, ca[2]={0.f,0.f}, ga[2]={0.f,0.f};
        const float4* t4=(const float4*)(tuw+f*128);
        const float4* c4=(const float4*)(cuw+f*128);
        const float4* f4=(const float4*)(fgw+f*128);
        #pragma unroll 8
        for (int i4=0;i4<32;++i4){
            float4 wt=t4[i4], wc=c4[i4], wf=f4[i4];
            #pragma unroll
            for (int u=0;u<2;++u){
                float4 a=((const float4*)(hnS+(rr2*2+u)*128))[i4];
                ta[u]=fmaxf(ta[u],fmaxf(fmaxf(a.x+wt.x,a.y+wt.y),fmaxf(a.z+wt.z,a.w+wt.w)));
                ca[u]=fmaf(a.x,wc.x,fmaf(a.y,wc.y,fmaf(a.z,wc.z,fmaf(a.w,wc.w,ca[u]))));
                ga[u]=fmaf(a.x,wf.x,fmaf(a.y,wf.y,fmaf(a.z,wf.z,fmaf(a.w,wf.w,ga[u]))));
            }
        }
        float gl=sigm(lgG[f]);
        float lav[8],lcv[8];
        #pragma unroll
        for (int p=0;p<8;++p){ lav[p]=laA[p*256+f]; lcv[p]=laC[p*256+f]; }
        float tubf=tub[f], cubf=cub[f], fgbf=fgb[f];
        #pragma unroll
        for (int u=0;u<2;++u){
            float z=ta[u]+tubf;
            float mx=-1e30f, mn=1e30f;
            #pragma unroll
            for (int p=0;p<8;++p){
                float zp=fmaf(z,lav[p],lcv[p]);
                mx=fmaxf(mx,zp); mn=fminf(mn,zp);
            }
            float trop=gl*mx+(1.f-gl)*mn;
            float xc=ca[u]+cubf;
            float cla=0.5f*xc*(1.f+erff(xc*0.70710678118654752f));
            float gf=sigm(ga[u]+fgbf);
            fusedS[(rr2*2+u)*256+f]=gf*trop+(1.f-gf)*cla;
        }
    }
    __syncthreads();

    // dproj split-K=4 (64 floats each)
    {
        float acc2[4]={0.f,0.f,0.f,0.f};
        const float4* w4b=(const float4*)(dnw + d*256);
        #pragma unroll 4
        for (int i4=0;i4<16;++i4){
            int ii=s*16+i4;
            float4 w=w4b[ii];
            #pragma unroll
            for (int r=0;r<4;++r){
                float4 a=((const float4*)(fusedS+r*256))[ii];
                acc2[r]=fmaf(a.x,w.x,fmaf(a.y,w.y,fmaf(a.z,w.z,fmaf(a.w,w.w,acc2[r]))));
            }
        }
        __syncthreads();
        #pragma unroll
        for (int r=0;r<4;++r) pacc[(s*4+r)*128+d]=acc2[r];
    }
    __syncthreads();
    if (t<128){
        #pragma unroll
        for (int r=0;r<4;++r){
            hres[r]+=pacc[r*128+d]+pacc[(4+r)*128+d]+pacc[(8+r)*128+d]+pacc[(12+r)*128+d]+dnb[d];
            if (!FINAL) h[(r0+r)*128+d]=hres[r];
        }
    }
    ln_rows(hres, nlw, nlb, hnS, red, t);

    if (!FINAL) {
        qkvg512(hnS, r0, t, wq,bq,wk,bk,wv,bv,gw,gb, Q,Kg,V,g);
    } else {
        int crow=-1, cb2=0;
        #pragma unroll
        for (int r=0;r<4;++r){
            int row=r0+r;
            if (row==0 || row==197 || row==394 || row==591){ crow=r; cb2=row/197; }
        }
        if (crow>=0){
            const float4* hc=(const float4*)(hnS+crow*128);
            for (int n=t;n<1000;n+=512){
                const float4* wr=(const float4*)(hdw+(size_t)n*128);
                float a2=hdb[n];
                #pragma unroll 8
                for (int i=0;i<32;++i){
                    float4 w=wr[i], a=hc[i];
                    a2=fmaf(w.x,a.x,fmaf(w.y,a.y,fmaf(w.z,a.z,fmaf(w.w,a.w,a2))));
                }
                out[cb2*1000+n]=a2;
            }
        }
    }
}

// ---------------------------------------------------------------------------
extern "C" void kernel_launch(void* const* d_in, const int* in_sizes, int n_in,
                              void* d_out, int out_size, void* d_ws, size_t ws_size,
                              hipStream_t stream)
{
    const float* x        = (const float*)d_in[0];
    const float* patch_w  = (const float*)d_in[1];
    const float* patch_b  = (const float*)d_in[2];
    const float* cls_tok  = (const float*)d_in[3];
    const float* pos_emb  = (const float*)d_in[4];
    const float* bn_gamma = (const float*)d_in[5];
    const float* bn_beta  = (const float*)d_in[6];
    const float* bn_rmax  = (const float*)d_in[7];
    const float* bn_rrng  = (const float*)d_in[8];
    const float* n1_w     = (const float*)d_in[9];
    const float* n1_b     = (const float*)d_in[10];
    const float* n2_w     = (const float*)d_in[11];
    const float* n2_b     = (const float*)d_in[12];
    const float* wq       = (const float*)d_in[13];
    const float* bq       = (const float*)d_in[14];
    const float* wk       = (const float*)d_in[15];
    const float* bk       = (const float*)d_in[16];
    const float* wv       = (const float*)d_in[17];
    const float* bv       = (const float*)d_in[18];
    const float* wo       = (const float*)d_in[19];
    const float* bo       = (const float*)d_in[20];
    const float* gate_w   = (const float*)d_in[21];
    const float* gate_b   = (const float*)d_in[22];
    const float* temp     = (const float*)d_in[23];
    const float* tu_w     = (const float*)d_in[24];
    const float* tu_b     = (const float*)d_in[25];
    const float* lf_a     = (const float*)d_in[26];
    const float* lf_c     = (const float*)d_in[27];
    const float* lf_gate  = (const float*)d_in[28];
    const float* cu_w     = (const float*)d_in[29];
    const float* cu_b     = (const float*)d_in[30];
    const float* fg_w     = (const float*)d_in[31];
    const float* fg_b     = (const float*)d_in[32];
    const float* dn_w     = (const float*)d_in[33];
    const float* dn_b     = (const float*)d_in[34];
    const float* fn_w     = (const float*)d_in[35];
    const float* fn_b     = (const float*)d_in[36];
    const float* head_w   = (const float*)d_in[37];
    const float* head_b   = (const float*)d_in[38];

    float* ws = (float*)d_ws;
    float* h   = ws;                 // 788*128
    float* Q   = ws + 100864;
    float* Kb  = Q  + 100864;
    float* V   = Kb + 100864;
    float* g   = V  + 100864;        // 788*8
    float* ao  = g  + 6304;          // 788*128
    float* out = (float*)d_out;

    k_p1<<<197, 512, 0, stream>>>(x, patch_w, patch_b, cls_tok, pos_emb,
                                  bn_gamma, bn_beta, bn_rmax, bn_rrng,
                                  n1_w, n1_b,
                                  wq, bq, wk, bk, wv, bv, gate_w, gate_b,
                                  h, Q, Kb, V, g);

    k_attn<<<224, 256, 0, stream>>>(Q, Kb, V, g, temp, ao);

    k_p34<0><<<197, 512, 0, stream>>>(ao, h,
        wo, bo, n2_w, n2_b,
        tu_w, tu_b, lf_a, lf_c, lf_gate,
        cu_w, cu_b, fg_w, fg_b, dn_w, dn_b,
        n1_w + 128, n1_b + 128,
        wq + 16384, bq + 128, wk + 16384, bk + 128, wv + 16384, bv + 128,
        gate_w + 1024, gate_b + 8,
        Q, Kb, V, g, nullptr, nullptr, nullptr);

    k_attn<<<224, 256, 0, stream>>>(Q, Kb, V, g, temp + 8, ao);

    k_p34<1><<<197, 512, 0, stream>>>(ao, h,
        wo + 16384, bo + 128, n2_w + 128, n2_b + 128,
        tu_w + 32768, tu_b + 256, lf_a + 2048, lf_c + 2048, lf_gate + 256,
        cu_w + 32768, cu_b + 256, fg_w + 32768, fg_b + 256, dn_w + 32768, dn_b + 128,
        fn_w, fn_b,
        nullptr, nullptr, nullptr, nullptr, nullptr, nullptr, nullptr, nullptr,
        Q, Kb, V, g, head_w, head_b, out);
}

// Round 4
// 107.851 us; speedup vs baseline: 3.7706x; 1.4326x over previous
//
#include <hip/hip_runtime.h>
#include <math.h>

#define EPSF 1e-5f

__device__ __forceinline__ float sigm(float v){ return 1.f/(1.f+__expf(-v)); }

// ---------------------------------------------------------------------------
// ws layout (floats)
// ---------------------------------------------------------------------------
#define WS_H    0
#define WS_Q    100864
#define WS_K    201728
#define WS_V    302592
#define WS_G    403456
#define WS_AO   409760
#define WS_PWT  510624
#define WS_WQT  608928
#define WS_WKT  641696
#define WS_WVT  674464
#define WS_WOT  707232
#define WS_GWT  740000
#define WS_TUT  742048
#define WS_CUT  807584
#define WS_FGT  873120
#define WS_DNT  938656
#define WS_HDT  1004192
// end: 1132192 floats = 4.53 MB

// ---------------------------------------------------------------------------
// K0: transpose all weight matrices (dst[m][k*N+n] = src[m][n*K+k])
// ---------------------------------------------------------------------------
__global__ __launch_bounds__(256) void k_tr(
    const float* __restrict__ pw, const float* __restrict__ wq, const float* __restrict__ wk,
    const float* __restrict__ wv, const float* __restrict__ wo, const float* __restrict__ gw,
    const float* __restrict__ tu, const float* __restrict__ cu, const float* __restrict__ fg,
    const float* __restrict__ dn, const float* __restrict__ hd, float* __restrict__ ws)
{
    long gid = (long)blockIdx.x * blockDim.x + threadIdx.x;
    long gstride = (long)gridDim.x * blockDim.x;
#define TR(src, dstoff, NN, KK, CNT)                                              \
    for (long i = gid; i < (long)(NN)*(KK)*(CNT); i += gstride) {                 \
        long m = i / ((long)(NN)*(KK)); long rdm = i - m*(long)(NN)*(KK);         \
        long k = rdm / (NN); long n = rdm - k*(NN);                               \
        ws[(dstoff) + m*(long)(NN)*(KK) + k*(NN) + n] = (src)[m*(long)(NN)*(KK) + n*(KK) + k]; }
    TR(pw, WS_PWT, 128, 768, 1)
    TR(wq, WS_WQT, 128, 128, 2)
    TR(wk, WS_WKT, 128, 128, 2)
    TR(wv, WS_WVT, 128, 128, 2)
    TR(wo, WS_WOT, 128, 128, 2)
    TR(gw, WS_GWT, 8, 128, 2)
    TR(tu, WS_TUT, 256, 128, 2)
    TR(cu, WS_CUT, 256, 128, 2)
    TR(fg, WS_FGT, 256, 128, 2)
    TR(dn, WS_DNT, 128, 256, 2)
    TR(hd, WS_HDT, 1000, 128, 1)
#undef TR
}

// LayerNorm of 4 rows; values hv[4] held by threads t<128; out -> hnS[4][128]
__device__ __forceinline__ void ln_rows(const float hv[4],
    const float* __restrict__ lw, const float* __restrict__ lb,
    float* hnS, float* red, int t)
{
    int d = t & 127;
    if (t < 128) {
        float s[4], s2[4];
        #pragma unroll
        for (int r=0;r<4;++r){ s[r]=hv[r]; s2[r]=hv[r]*hv[r]; }
        #pragma unroll
        for (int o=1;o<64;o<<=1){
            #pragma unroll
            for (int r=0;r<4;++r){ s[r]+=__shfl_xor(s[r],o); s2[r]+=__shfl_xor(s2[r],o); }
        }
        if ((t & 63)==0){
            int wid = t>>6;
            #pragma unroll
            for (int r=0;r<4;++r){ red[r*2+wid]=s[r]; red[8+r*2+wid]=s2[r]; }
        }
    }
    __syncthreads();
    if (t < 128) {
        #pragma unroll
        for (int r=0;r<4;++r){
            float S=red[r*2]+red[r*2+1], S2=red[8+r*2]+red[8+r*2+1];
            float mu=S*(1.f/128.f), var=S2*(1.f/128.f)-mu*mu;
            float rr=rsqrtf(var+EPSF);
            hnS[r*128+d]=(hv[r]-mu)*rr*lw[d]+lb[d];
        }
    }
    __syncthreads();
}

// QKV (transposed weights, coalesced) + gate.  512 threads.
__device__ __forceinline__ void qkvgT(const float* hnS, int r0, int t,
    const float* __restrict__ wqT, const float* __restrict__ bq,
    const float* __restrict__ wkT, const float* __restrict__ bk,
    const float* __restrict__ wvT, const float* __restrict__ bv,
    const float* __restrict__ gwT, const float* __restrict__ gb,
    float* __restrict__ Q, float* __restrict__ Kg, float* __restrict__ V,
    float* __restrict__ g)
{
    int mat = t >> 7;
    if (mat < 3) {
        int q4i = t & 31, r = (t >> 5) & 3;
        const float* wT = (mat==0) ? wqT : (mat==1) ? wkT : wvT;
        const float4* w4 = (const float4*)wT + q4i;
        const float* a = hnS + r*128;
        float a0,a1,a2,a3;
        if (mat < 2) {
            a0=a1=a2=a3=-1e30f;
            #pragma unroll 8
            for (int k=0;k<128;++k){
                float4 w = w4[k*32];
                float av = a[k];
                a0=fmaxf(a0,av+w.x); a1=fmaxf(a1,av+w.y);
                a2=fmaxf(a2,av+w.z); a3=fmaxf(a3,av+w.w);
            }
        } else {
            a0=a1=a2=a3=0.f;
            #pragma unroll 8
            for (int k=0;k<128;++k){
                float4 w = w4[k*32];
                float av = a[k];
                a0=fmaf(av,w.x,a0); a1=fmaf(av,w.y,a1);
                a2=fmaf(av,w.z,a2); a3=fmaf(av,w.w,a3);
            }
        }
        int d0 = q4i*4;
        float* dst = (mat==0) ? Q : (mat==1) ? Kg : V;
        const float* bias = (mat==0) ? bq : (mat==1) ? bk : bv;
        float4 o4 = {a0+bias[d0], a1+bias[d0+1], a2+bias[d0+2], a3+bias[d0+3]};
        *(float4*)(dst + (size_t)(r0+r)*128 + d0) = o4;
    } else {
        int u = t & 127, r = u>>5, hh=(u>>2)&7, ks=u&3;
        const float* a = hnS + r*128;
        float acc = 0.f;
        #pragma unroll 8
        for (int k=ks*32;k<ks*32+32;++k) acc = fmaf(a[k], gwT[k*8+hh], acc);
        acc += __shfl_xor(acc,1);
        acc += __shfl_xor(acc,2);
        if (ks==0) g[(r0+r)*8+hh] = sigm(acc + gb[hh]);
    }
}

// ---------------------------------------------------------------------------
// K1: patchify + patch embed + BN + LN1 + QKVG(layer0).  197 blocks x 512
// ---------------------------------------------------------------------------
__global__ __launch_bounds__(512) void k_p1(
    const float* __restrict__ x, const float* __restrict__ pwT, const float* __restrict__ pb,
    const float* __restrict__ clsT, const float* __restrict__ pos,
    const float* __restrict__ bng, const float* __restrict__ bnb,
    const float* __restrict__ bnm, const float* __restrict__ bnr,
    const float* __restrict__ n1w, const float* __restrict__ n1b,
    const float* __restrict__ wqT, const float* __restrict__ bq,
    const float* __restrict__ wkT, const float* __restrict__ bk,
    const float* __restrict__ wvT, const float* __restrict__ bv,
    const float* __restrict__ gwT, const float* __restrict__ gb,
    float* __restrict__ h, float* __restrict__ Q, float* __restrict__ Kg,
    float* __restrict__ V, float* __restrict__ g)
{
    __shared__ __align__(16) float xp[4*768];
    __shared__ __align__(16) float pacc[16*128];
    __shared__ __align__(16) float hnS[512];
    __shared__ float red[16];
    int t = threadIdx.x, r0 = blockIdx.x * 4;

    // stage patches (coalesced)
    #pragma unroll
    for (int r=0;r<4;++r){
        int row=r0+r, b=row/197, l=row-b*197;
        if (l>0){
            int patch=l-1, ph=patch/14, pc=patch-ph*14;
            const float* xb = x + (size_t)b*150528 + ph*3584 + pc*16;
            for (int i=t;i<768;i+=512){
                int c=i>>8, rr=(i>>4)&15, cc=i&15;
                xp[r*768+i] = xb[c*50176 + rr*224 + cc];
            }
        }
    }
    __syncthreads();

    // patch GEMM: transposed weights, d-quad per lane, split-K=4
    {
        int q4i = t & 31, sel = t >> 5, r = sel & 3, ks = sel >> 2;
        float a0=0.f,a1=0.f,a2=0.f,a3=0.f;
        const float4* w4 = (const float4*)pwT + q4i;
        const float* a = xp + r*768;
        #pragma unroll 8
        for (int k=ks*192;k<ks*192+192;++k){
            float4 w = w4[k*32];
            float av = a[k];
            a0=fmaf(av,w.x,a0); a1=fmaf(av,w.y,a1);
            a2=fmaf(av,w.z,a2); a3=fmaf(av,w.w,a3);
        }
        float4 o4={a0,a1,a2,a3};
        *(float4*)(pacc + sel*128 + q4i*4) = o4;
    }
    __syncthreads();

    float hres[4]={0.f,0.f,0.f,0.f};
    if (t < 128){
        int d=t;
        #pragma unroll
        for (int r=0;r<4;++r){
            int row=r0+r, l=row%197;
            float v = (l==0) ? clsT[d]
                    : (pacc[r*128+d]+pacc[(4+r)*128+d]+pacc[(8+r)*128+d]+pacc[(12+r)*128+d]+pb[d]);
            v += pos[l*128+d];
            v = bng[d]*((v-bnm[d])/(bnr[d]+EPSF))+bnb[d];
            hres[r]=v;
            h[row*128+d]=v;
        }
    }
    ln_rows(hres, n1w, n1b, hnS, red, t);
    qkvgT(hnS, r0, t, wqT,bq,wkT,bk,wvT,bv,gwT,gb, Q,Kg,V,g);
}

// ---------------------------------------------------------------------------
// K2: fused attention.  224 blocks x 256 threads (8 lanes per query)
// K/V LDS rows padded 16->20 floats to dodge bank conflicts.
// ---------------------------------------------------------------------------
__global__ __launch_bounds__(256) void k_attn(
    const float* __restrict__ Qd, const float* __restrict__ Kd,
    const float* __restrict__ Vd, const float* __restrict__ gd,
    const float* __restrict__ tempL, float* __restrict__ ao)
{
    __shared__ __align__(16) float Ks[197*20];
    __shared__ __align__(16) float Vs[197*20];
    int bid = blockIdx.x, t = threadIdx.x;
    int qc = bid % 7, bh = bid / 7, hh = bh & 7, b = bh >> 3;
    size_t base = (size_t)(b*197)*128 + hh*16;

    {
        const float4* ksrc=(const float4*)(Kd+base);
        const float4* vsrc=(const float4*)(Vd+base);
        float4* kdst=(float4*)Ks; float4* vdst=(float4*)Vs;
        for (int idx=t; idx<788; idx+=256){
            int l=idx>>2, jj=idx&3;
            kdst[l*5+jj]=ksrc[l*32+jj];
            vdst[l*5+jj]=vsrc[l*32+jj];
        }
    }
    __syncthreads();

    int q = qc*32 + (t>>3), j8 = t&7;
    if (q >= 197) return;

    float Qr[16];
    {
        const float4* qp=(const float4*)(Qd+base+(size_t)q*128);
        #pragma unroll
        for (int u=0;u<4;++u){
            float4 v=qp[u];
            Qr[4*u]=v.x; Qr[4*u+1]=v.y; Qr[4*u+2]=v.z; Qr[4*u+3]=v.w;
        }
    }
    float gq = gd[(b*197+q)*8+hh];
    float it = 0.25f / tempL[hh];
    float gg = gq*it, cg = (1.f-gq)*it;

    float m=-1e30f, lsum=0.f, o[16];
    #pragma unroll
    for (int j=0;j<16;++j) o[j]=0.f;

    for (int k=j8;k<197;k+=8){
        const float4* kr4=(const float4*)(Ks+k*20);
        float4 kv0=kr4[0], kv1=kr4[1], kv2=kr4[2], kv3=kr4[3];
        float kr[16] = {kv0.x,kv0.y,kv0.z,kv0.w, kv1.x,kv1.y,kv1.z,kv1.w,
                        kv2.x,kv2.y,kv2.z,kv2.w, kv3.x,kv3.y,kv3.z,kv3.w};
        float cs=0.f, ts=-1e30f;
        #pragma unroll
        for (int j=0;j<16;++j){
            cs=fmaf(Qr[j],kr[j],cs);
            ts=fmaxf(ts,Qr[j]+kr[j]);
        }
        float sc=fmaf(gg,ts,cg*cs);
        if (sc>m){
            float c=__expf(m-sc);
            lsum*=c;
            #pragma unroll
            for (int j=0;j<16;++j) o[j]*=c;
            m=sc;
        }
        float p=__expf(sc-m);
        lsum+=p;
        const float4* vr4=(const float4*)(Vs+k*20);
        float4 vv0=vr4[0], vv1=vr4[1], vv2=vr4[2], vv3=vr4[3];
        float vr[16] = {vv0.x,vv0.y,vv0.z,vv0.w, vv1.x,vv1.y,vv1.z,vv1.w,
                        vv2.x,vv2.y,vv2.z,vv2.w, vv3.x,vv3.y,vv3.z,vv3.w};
        #pragma unroll
        for (int j=0;j<16;++j) o[j]=fmaf(p,vr[j],o[j]);
    }

    #pragma unroll
    for (int mask=1;mask<8;mask<<=1){
        float mo=__shfl_xor(m,mask), lo=__shfl_xor(lsum,mask);
        float mn=fmaxf(m,mo);
        float ea=__expf(m-mn), eb=__expf(mo-mn);
        lsum=lsum*ea+lo*eb;
        #pragma unroll
        for (int j=0;j<16;++j){
            float oo=__shfl_xor(o[j],mask);
            o[j]=o[j]*ea+oo*eb;
        }
        m=mn;
    }

    if (j8==0){
        float inv=1.f/lsum;
        float* orow=ao+base+(size_t)q*128;
        #pragma unroll
        for (int j=0;j<16;++j) orow[j]=o[j]*inv;
    }
}

// ---------------------------------------------------------------------------
// K3: oproj+res+LN2 + FFN + dproj+res + next-LN + (QKVG | head)
// 197 blocks x 512 threads; all weights transposed (coalesced streams)
// ---------------------------------------------------------------------------
template <int FINAL>
__global__ __launch_bounds__(512) void k_p34(
    const float* __restrict__ ao, float* __restrict__ h,
    const float* __restrict__ woT, const float* __restrict__ bo,
    const float* __restrict__ n2w, const float* __restrict__ n2b,
    const float* __restrict__ tuT, const float* __restrict__ tub,
    const float* __restrict__ laA, const float* __restrict__ laC,
    const float* __restrict__ lgG,
    const float* __restrict__ cuT, const float* __restrict__ cub,
    const float* __restrict__ fgT, const float* __restrict__ fgb,
    const float* __restrict__ dnT, const float* __restrict__ dnb,
    const float* __restrict__ nlw, const float* __restrict__ nlb,
    const float* __restrict__ wqT, const float* __restrict__ bq,
    const float* __restrict__ wkT, const float* __restrict__ bk,
    const float* __restrict__ wvT, const float* __restrict__ bv,
    const float* __restrict__ gwT, const float* __restrict__ gb,
    float* __restrict__ Q, float* __restrict__ Kg, float* __restrict__ V,
    float* __restrict__ g,
    const float* __restrict__ hdT, const float* __restrict__ hdb,
    float* __restrict__ out)
{
    __shared__ __align__(16) float aoS[512];
    __shared__ __align__(16) float pacc[16*128];
    __shared__ __align__(16) float hnS[512];
    __shared__ __align__(16) float zS[3*1024];
    __shared__ __align__(16) float fusedS[1024];
    __shared__ float red[16];
    int t = threadIdx.x, r0 = blockIdx.x * 4;

    aoS[t] = ao[(size_t)r0*128 + t];
    __syncthreads();

    // oproj: d-quad per lane, split-K=4 (32 k each)
    {
        int q4i=t&31, sel=t>>5, r=sel&3, ks=sel>>2;
        float a0=0.f,a1=0.f,a2=0.f,a3=0.f;
        const float4* w4=(const float4*)woT + q4i;
        const float* a = aoS + r*128;
        #pragma unroll 8
        for (int k=ks*32;k<ks*32+32;++k){
            float4 w=w4[k*32];
            float av=a[k];
            a0=fmaf(av,w.x,a0); a1=fmaf(av,w.y,a1);
            a2=fmaf(av,w.z,a2); a3=fmaf(av,w.w,a3);
        }
        float4 o4={a0,a1,a2,a3};
        *(float4*)(pacc + sel*128 + q4i*4)=o4;
    }
    __syncthreads();

    float hres[4]={0.f,0.f,0.f,0.f};
    if (t<128){
        int d=t;
        #pragma unroll
        for (int r=0;r<4;++r)
            hres[r]=h[(r0+r)*128+d]+pacc[r*128+d]+pacc[(4+r)*128+d]+pacc[(8+r)*128+d]+pacc[(12+r)*128+d]+bo[d];
    }
    ln_rows(hres, n2w, n2b, hnS, red, t);

    // FFN matmuls: 6 tasks (3 matrices x 2 row-pairs), f-quad per lane
    if (t < 384) {
        int task=t>>6, fq=t&63, mat=task>>1, rp=task&1;
        const float* wT = (mat==0)? tuT : (mat==1)? cuT : fgT;
        const float4* w4=(const float4*)wT + fq;
        const float* A0 = hnS + (2*rp)*128;
        const float* A1 = hnS + (2*rp+1)*128;
        float4 acc0, acc1;
        if (mat==0){ acc0.x=acc0.y=acc0.z=acc0.w=-1e30f; acc1=acc0; }
        else       { acc0.x=acc0.y=acc0.z=acc0.w=0.f;    acc1=acc0; }
        if (mat==0){
            #pragma unroll 8
            for (int k=0;k<128;++k){
                float4 w=w4[k*64];
                float av0=A0[k], av1=A1[k];
                acc0.x=fmaxf(acc0.x,av0+w.x); acc0.y=fmaxf(acc0.y,av0+w.y);
                acc0.z=fmaxf(acc0.z,av0+w.z); acc0.w=fmaxf(acc0.w,av0+w.w);
                acc1.x=fmaxf(acc1.x,av1+w.x); acc1.y=fmaxf(acc1.y,av1+w.y);
                acc1.z=fmaxf(acc1.z,av1+w.z); acc1.w=fmaxf(acc1.w,av1+w.w);
            }
        } else {
            #pragma unroll 8
            for (int k=0;k<128;++k){
                float4 w=w4[k*64];
                float av0=A0[k], av1=A1[k];
                acc0.x=fmaf(av0,w.x,acc0.x); acc0.y=fmaf(av0,w.y,acc0.y);
                acc0.z=fmaf(av0,w.z,acc0.z); acc0.w=fmaf(av0,w.w,acc0.w);
                acc1.x=fmaf(av1,w.x,acc1.x); acc1.y=fmaf(av1,w.y,acc1.y);
                acc1.z=fmaf(av1,w.z,acc1.z); acc1.w=fmaf(av1,w.w,acc1.w);
            }
        }
        *(float4*)(zS + mat*1024 + (2*rp)*256 + fq*4)   = acc0;
        *(float4*)(zS + mat*1024 + (2*rp+1)*256 + fq*4) = acc1;
    }
    __syncthreads();

    // FFN epilogue: 2 (r,f) slots per thread
    #pragma unroll
    for (int s2=0;s2<2;++s2){
        int slot = t + s2*512;
        int r = slot>>8, f = slot&255;
        float z  = zS[r*256+f] + tub[f];
        float xc = zS[1024 + r*256+f] + cub[f];
        float gv = zS[2048 + r*256+f] + fgb[f];
        float gl = sigm(lgG[f]);
        float mx=-1e30f, mn=1e30f;
        #pragma unroll
        for (int p=0;p<8;++p){
            float zp=fmaf(z, laA[p*256+f], laC[p*256+f]);
            mx=fmaxf(mx,zp); mn=fminf(mn,zp);
        }
        float trop=gl*mx+(1.f-gl)*mn;
        float cla=0.5f*xc*(1.f+erff(xc*0.70710678118654752f));
        float gf=sigm(gv);
        fusedS[r*256+f]=gf*trop+(1.f-gf)*cla;
    }
    __syncthreads();

    // dproj: d-quad per lane, split-K=4 (64 k each)
    {
        int q4i=t&31, sel=t>>5, r=sel&3, ks=sel>>2;
        float a0=0.f,a1=0.f,a2=0.f,a3=0.f;
        const float4* w4=(const float4*)dnT + q4i;
        const float* a = fusedS + r*256;
        #pragma unroll 8
        for (int k=ks*64;k<ks*64+64;++k){
            float4 w=w4[k*32];
            float av=a[k];
            a0=fmaf(av,w.x,a0); a1=fmaf(av,w.y,a1);
            a2=fmaf(av,w.z,a2); a3=fmaf(av,w.w,a3);
        }
        float4 o4={a0,a1,a2,a3};
        *(float4*)(pacc + sel*128 + q4i*4)=o4;
    }
    __syncthreads();
    if (t<128){
        int d=t;
        #pragma unroll
        for (int r=0;r<4;++r){
            hres[r]+=pacc[r*128+d]+pacc[(4+r)*128+d]+pacc[(8+r)*128+d]+pacc[(12+r)*128+d]+dnb[d];
            if (!FINAL) h[(r0+r)*128+d]=hres[r];
        }
    }
    ln_rows(hres, nlw, nlb, hnS, red, t);

    if (!FINAL) {
        qkvgT(hnS, r0, t, wqT,bq,wkT,bk,wvT,bv,gwT,gb, Q,Kg,V,g);
    } else {
        int crow=-1, cb2=0;
        #pragma unroll
        for (int r=0;r<4;++r){
            int row=r0+r;
            if (row==0 || row==197 || row==394 || row==591){ crow=r; cb2=row/197; }
        }
        if (crow>=0 && t<500){
            const float2* w2=(const float2*)hdT + t;   // hdT[k*1000+n], 500 float2 per k
            const float* a = hnS + crow*128;
            float acc0=hdb[2*t], acc1=hdb[2*t+1];
            #pragma unroll 8
            for (int k=0;k<128;++k){
                float2 w=w2[k*500];
                float av=a[k];
                acc0=fmaf(av,w.x,acc0); acc1=fmaf(av,w.y,acc1);
            }
            out[cb2*1000+2*t]=acc0;
            out[cb2*1000+2*t+1]=acc1;
        }
    }
}

// ---------------------------------------------------------------------------
extern "C" void kernel_launch(void* const* d_in, const int* in_sizes, int n_in,
                              void* d_out, int out_size, void* d_ws, size_t ws_size,
                              hipStream_t stream)
{
    const float* x        = (const float*)d_in[0];
    const float* patch_w  = (const float*)d_in[1];
    const float* patch_b  = (const float*)d_in[2];
    const float* cls_tok  = (const float*)d_in[3];
    const float* pos_emb  = (const float*)d_in[4];
    const float* bn_gamma = (const float*)d_in[5];
    const float* bn_beta  = (const float*)d_in[6];
    const float* bn_rmax  = (const float*)d_in[7];
    const float* bn_rrng  = (const float*)d_in[8];
    const float* n1_w     = (const float*)d_in[9];
    const float* n1_b     = (const float*)d_in[10];
    const float* n2_w     = (const float*)d_in[11];
    const float* n2_b     = (const float*)d_in[12];
    const float* wq       = (const float*)d_in[13];
    const float* bq       = (const float*)d_in[14];
    const float* wk       = (const float*)d_in[15];
    const float* bk       = (const float*)d_in[16];
    const float* wv       = (const float*)d_in[17];
    const float* bv       = (const float*)d_in[18];
    const float* wo       = (const float*)d_in[19];
    const float* bo       = (const float*)d_in[20];
    const float* gate_w   = (const float*)d_in[21];
    const float* gate_b   = (const float*)d_in[22];
    const float* temp     = (const float*)d_in[23];
    const float* tu_w     = (const float*)d_in[24];
    const float* tu_b     = (const float*)d_in[25];
    const float* lf_a     = (const float*)d_in[26];
    const float* lf_c     = (const float*)d_in[27];
    const float* lf_gate  = (const float*)d_in[28];
    const float* cu_w     = (const float*)d_in[29];
    const float* cu_b     = (const float*)d_in[30];
    const float* fg_w     = (const float*)d_in[31];
    const float* fg_b     = (const float*)d_in[32];
    const float* dn_w     = (const float*)d_in[33];
    const float* dn_b     = (const float*)d_in[34];
    const float* fn_w     = (const float*)d_in[35];
    const float* fn_b     = (const float*)d_in[36];
    const float* head_w   = (const float*)d_in[37];
    const float* head_b   = (const float*)d_in[38];

    float* ws = (float*)d_ws;
    float* h   = ws + WS_H;
    float* Q   = ws + WS_Q;
    float* Kb  = ws + WS_K;
    float* V   = ws + WS_V;
    float* g   = ws + WS_G;
    float* ao  = ws + WS_AO;
    float* out = (float*)d_out;

    k_tr<<<256, 256, 0, stream>>>(patch_w, wq, wk, wv, wo, gate_w,
                                  tu_w, cu_w, fg_w, dn_w, head_w, ws);

    k_p1<<<197, 512, 0, stream>>>(x, ws+WS_PWT, patch_b, cls_tok, pos_emb,
                                  bn_gamma, bn_beta, bn_rmax, bn_rrng,
                                  n1_w, n1_b,
                                  ws+WS_WQT, bq, ws+WS_WKT, bk, ws+WS_WVT, bv,
                                  ws+WS_GWT, gate_b,
                                  h, Q, Kb, V, g);

    k_attn<<<224, 256, 0, stream>>>(Q, Kb, V, g, temp, ao);

    k_p34<0><<<197, 512, 0, stream>>>(ao, h,
        ws+WS_WOT, bo, n2_w, n2_b,
        ws+WS_TUT, tu_b, lf_a, lf_c, lf_gate,
        ws+WS_CUT, cu_b, ws+WS_FGT, fg_b, ws+WS_DNT, dn_b,
        n1_w + 128, n1_b + 128,
        ws+WS_WQT+16384, bq + 128, ws+WS_WKT+16384, bk + 128,
        ws+WS_WVT+16384, bv + 128, ws+WS_GWT+1024, gate_b + 8,
        Q, Kb, V, g, nullptr, nullptr, nullptr);

    k_attn<<<224, 256, 0, stream>>>(Q, Kb, V, g, temp + 8, ao);

    k_p34<1><<<197, 512, 0, stream>>>(ao, h,
        ws+WS_WOT+16384, bo + 128, n2_w + 128, n2_b + 128,
        ws+WS_TUT+32768, tu_b + 256, lf_a + 2048, lf_c + 2048, lf_gate + 256,
        ws+WS_CUT+32768, cu_b + 256, ws+WS_FGT+32768, fg_b + 256,
        ws+WS_DNT+32768, dn_b + 128,
        fn_w, fn_b,
        nullptr, nullptr, nullptr, nullptr, nullptr, nullptr, nullptr, nullptr,
        Q, Kb, V, g, ws+WS_HDT, head_b, out);
}